// Round 3
// baseline (21741.533 us; speedup 1.0000x reference)
//
#include <hip/hip_runtime.h>
#include <stdint.h>

// ---------------------------------------------------------------------------
// 2-layer LSTM (B=256, T=512, IN=64, H=256) + linear head, persistent kernel.
//
// Grid 256 x 256 threads. bg = bid&7 (batch group of 32), role = bid>>3:
//   role 0..15  -> layer-0 block, feature slice role&15 (16 h-features)
//   role 16..31 -> layer-1 block, feature slice role&15
// Per block: 4 waves = (M-half mh) x (K-half kh). Weights held in registers
// as MFMA B-fragments, split into hi/lo bf16 (hi = bf16(w), lo = bf16(w-hi)).
// gates = Whi@hhi + Whi@hlo + Wlo@hhi  (drop Wlo@hlo, ~2^-18 relative).
// h is exchanged via d_ws in fragment-major bf16 hi/lo planes; producers
// signal cumulative per-group flags (release), consumers spin (acquire).
// ---------------------------------------------------------------------------

#define TT 512

typedef short short8 __attribute__((ext_vector_type(8)));
typedef float f32x4 __attribute__((ext_vector_type(4)));

#define H0_OFF   0
#define H1_OFF   524288      // 2 bufs * 8 bg * 2 comp * 1024 units * 16B
#define FLAGS_OFF 1048576
#define WS_BYTES (1048576 + 4096)

static __device__ __forceinline__ short8 as_short8(uint4 v) {
  union { uint4 u; short8 s; } c; c.u = v; return c.s;
}

static __device__ __forceinline__ unsigned short f2bf(float f) {
  uint32_t u = __float_as_uint(f);
  u += 0x7fffu + ((u >> 16) & 1u);          // round-to-nearest-even
  return (unsigned short)(u >> 16);
}
static __device__ __forceinline__ float bf2f(unsigned short b) {
  return __uint_as_float(((uint32_t)b) << 16);
}

static __device__ __forceinline__ void pack_hilo(float4 a, float4 b,
                                                 short8& hi, short8& lo) {
  float v[8] = {a.x, a.y, a.z, a.w, b.x, b.y, b.z, b.w};
#pragma unroll
  for (int i = 0; i < 8; ++i) {
    unsigned short h = f2bf(v[i]);
    hi[i] = (short)h;
    lo[i] = (short)f2bf(v[i] - bf2f(h));
  }
}

static __device__ __forceinline__ float sigf(float x) {
  return 1.0f / (1.0f + __expf(-x));
}
static __device__ __forceinline__ float tanh_fast(float x) {
  float xx = fminf(fmaxf(x, -15.0f), 15.0f);
  float e = __expf(2.0f * xx);
  return (e - 1.0f) / (e + 1.0f);
}

static __device__ __forceinline__ f32x4 mfma16(short8 a, short8 b, f32x4 c) {
  return __builtin_amdgcn_mfma_f32_16x16x32_bf16(a, b, c, 0, 0, 0);
}

// all lanes of the calling wave spin (wave-uniform flag value)
static __device__ __forceinline__ void spin_ge(uint32_t* f, uint32_t tgt) {
  int guard = 0;
  while (__hip_atomic_load(f, __ATOMIC_ACQUIRE, __HIP_MEMORY_SCOPE_AGENT) < tgt) {
    __builtin_amdgcn_s_sleep(1);
    if (++guard > (1 << 22)) break;         // safety escape: corrupt, not hang
  }
}

__global__ __launch_bounds__(256, 1) void lstm2_kernel(
    const float* __restrict__ x,
    const float* __restrict__ Wih0, const float* __restrict__ Whh0,
    const float* __restrict__ bih0, const float* __restrict__ bhh0,
    const float* __restrict__ Wih1, const float* __restrict__ Whh1,
    const float* __restrict__ bih1, const float* __restrict__ bhh1,
    const float* __restrict__ Whead, const float* __restrict__ bhead,
    float* __restrict__ out, uint8_t* __restrict__ ws)
{
  const int bid   = blockIdx.x;
  const int bg    = bid & 7;          // batch group (XCD-local cluster)
  const int role  = bid >> 3;
  const int layer = role >> 4;        // 0 or 1
  const int fs    = role & 15;        // feature slice
  const int f0    = fs << 4;
  const int tid   = threadIdx.x;
  const int wave  = tid >> 6;
  const int lane  = tid & 63;
  const int mh    = (wave >> 1) & 1;  // M half (batch rows mh*16..+16)
  const int kh    = wave & 1;         // K half
  const int lrow  = lane & 15;
  const int kg    = lane >> 4;        // 0..3

  uint4* h0p = (uint4*)(ws + H0_OFF);
  uint4* h1p = (uint4*)(ws + H1_OFF);
  uint32_t* flags = (uint32_t*)(ws + FLAGS_OFF);
  uint32_t* flag0 = flags + bg * 128;
  uint32_t* flag1 = flags + bg * 128 + 64;

  __shared__ f32x4 pg[2][4][64];      // cross-kh partial gates exchange (8KB)

  // --------------------------- weight prep ---------------------------------
  // B-frag: col c = n*16 + lrow  ->  weight row R = n*256 + f0 + lrow
  //         k = kh*128 + kt*32 + kg*8   (K=256 matrices)
  short8 Bhi[2][4][4], Blo[2][4][4];  // [input][kt][n]; input1 = W_hh
  short8 Xhi[4], Xlo[4];              // layer-0 W_ih (K=64): k = kh*32+kg*8
  float bias[4] = {0, 0, 0, 0};
  float wh = 0.0f, bh = 0.0f;

  const float* WH = layer ? Whh1 : Whh0;
  const float* BI = layer ? bih1 : bih0;
  const float* BH = layer ? bhh1 : bhh0;

#pragma unroll
  for (int kt = 0; kt < 4; ++kt) {
#pragma unroll
    for (int n = 0; n < 4; ++n) {
      const int R = n * 256 + f0 + lrow;
      const int k = kh * 128 + kt * 32 + kg * 8;
      const float* p = WH + (size_t)R * 256 + k;
      pack_hilo(*(const float4*)p, *(const float4*)(p + 4),
                Bhi[1][kt][n], Blo[1][kt][n]);
    }
  }
  if (layer == 1) {
#pragma unroll
    for (int kt = 0; kt < 4; ++kt) {
#pragma unroll
      for (int n = 0; n < 4; ++n) {
        const int R = n * 256 + f0 + lrow;
        const int k = kh * 128 + kt * 32 + kg * 8;
        const float* p = Wih1 + (size_t)R * 256 + k;
        pack_hilo(*(const float4*)p, *(const float4*)(p + 4),
                  Bhi[0][kt][n], Blo[0][kt][n]);
      }
    }
  } else {
#pragma unroll
    for (int n = 0; n < 4; ++n) {
      const int R = n * 256 + f0 + lrow;
      const float* p = Wih0 + (size_t)R * 64 + kh * 32 + kg * 8;
      pack_hilo(*(const float4*)p, *(const float4*)(p + 4), Xhi[n], Xlo[n]);
    }
  }
  if (kh == 0) {
#pragma unroll
    for (int n = 0; n < 4; ++n) {
      const int R = n * 256 + f0 + lrow;
      bias[n] = BI[R] + BH[R];
    }
    if (layer == 1) { wh = Whead[f0 + lrow]; bh = bhead[0]; }
  }

  // h fragment plane: (buf, comp) -> 1024 uint4 units; unit = kc*32 + row
  const size_t pl00 = (size_t)((0 * 8 + bg) * 2 + 0) * 1024;
  const size_t pl01 = (size_t)((0 * 8 + bg) * 2 + 1) * 1024;
  const size_t pl10 = (size_t)((1 * 8 + bg) * 2 + 0) * 1024;
  const size_t pl11 = (size_t)((1 * 8 + bg) * 2 + 1) * 1024;

  const int kcS = (f0 >> 3) + (lrow >> 3);   // store k-chunk
  const int foS = lrow & 7;

  float cst[4] = {0, 0, 0, 0};

  if (layer == 0) {
    // ------------------------------ layer 0 --------------------------------
    const float* xbase =
        x + (size_t)(bg * 32 + mh * 16 + lrow) * TT * 64 + kh * 32 + kg * 8;
    for (int t = 0; t < TT; ++t) {
      // x fragments (independent of flags)
      float4 xa = *(const float4*)(xbase + (size_t)t * 64);
      float4 xb = *(const float4*)(xbase + (size_t)t * 64 + 4);
      short8 xhi, xlo;
      pack_hilo(xa, xb, xhi, xlo);

      f32x4 acc[4];
#pragma unroll
      for (int n = 0; n < 4; ++n) {
        acc[n] = (f32x4)(0.0f);
        acc[n] = mfma16(xhi, Xhi[n], acc[n]);
        acc[n] = mfma16(xlo, Xhi[n], acc[n]);
        acc[n] = mfma16(xhi, Xlo[n], acc[n]);
      }

      if (t > 0) spin_ge(flag0, 32u * (uint32_t)t);   // h0[t-1] ready
      const uint4* ph = h0p + (((t - 1) & 1) ? pl10 : pl00);
      const uint4* pl = h0p + (((t - 1) & 1) ? pl11 : pl01);
#pragma unroll
      for (int kt = 0; kt < 4; ++kt) {
        const int unit = (kh * 16 + kt * 4 + kg) * 32 + mh * 16 + lrow;
        short8 ahi = as_short8(ph[unit]);
        short8 alo = as_short8(pl[unit]);
#pragma unroll
        for (int n = 0; n < 4; ++n) {
          acc[n] = mfma16(ahi, Bhi[1][kt][n], acc[n]);
          acc[n] = mfma16(alo, Bhi[1][kt][n], acc[n]);
          acc[n] = mfma16(ahi, Blo[1][kt][n], acc[n]);
        }
      }

      if (kh == 1) {
#pragma unroll
        for (int n = 0; n < 4; ++n) pg[mh][n][lane] = acc[n];
      }
      __syncthreads();
      if (kh == 0) {
#pragma unroll
        for (int n = 0; n < 4; ++n) acc[n] += pg[mh][n][lane];
        // backpressure: L1 must have consumed h0[t-2] before we overwrite
        if (t > 1) spin_ge(flag1, 32u * (uint32_t)(t - 1));
        unsigned short* sh = (unsigned short*)(h0p + ((t & 1) ? pl10 : pl00));
        unsigned short* sl = (unsigned short*)(h0p + ((t & 1) ? pl11 : pl01));
#pragma unroll
        for (int r = 0; r < 4; ++r) {
          float gi = acc[0][r] + bias[0];
          float gf = acc[1][r] + bias[1];
          float gg = acc[2][r] + bias[2];
          float go = acc[3][r] + bias[3];
          float cc = sigf(gf) * cst[r] + sigf(gi) * tanh_fast(gg);
          cst[r] = cc;
          float hv = sigf(go) * tanh_fast(cc);
          const int b = mh * 16 + kg * 4 + r;
          unsigned short hh = f2bf(hv);
          unsigned short hl = f2bf(hv - bf2f(hh));
          sh[(kcS * 32 + b) * 8 + foS] = hh;
          sl[(kcS * 32 + b) * 8 + foS] = hl;
        }
        __threadfence();
        if (lane == 0)
          __hip_atomic_fetch_add(flag0, 1u, __ATOMIC_RELEASE,
                                 __HIP_MEMORY_SCOPE_AGENT);
      }
      __syncthreads();
    }
  } else {
    // ------------------------------ layer 1 --------------------------------
    for (int s = 0; s < TT; ++s) {
      if (s > 0) spin_ge(flag1, 32u * (uint32_t)s);   // h1[s-1] ready (peers)
      const uint4* p1h = h1p + (((s - 1) & 1) ? pl10 : pl00);
      const uint4* p1l = h1p + (((s - 1) & 1) ? pl11 : pl01);
      uint4 a1h[4], a1l[4];
#pragma unroll
      for (int kt = 0; kt < 4; ++kt) {
        const int unit = (kh * 16 + kt * 4 + kg) * 32 + mh * 16 + lrow;
        a1h[kt] = p1h[unit];
        a1l[kt] = p1l[unit];
      }

      spin_ge(flag0, 32u * (uint32_t)(s + 1));        // h0[s] ready
      const uint4* p0h = h0p + ((s & 1) ? pl10 : pl00);
      const uint4* p0l = h0p + ((s & 1) ? pl11 : pl01);

      f32x4 acc[4];
#pragma unroll
      for (int n = 0; n < 4; ++n) acc[n] = (f32x4)(0.0f);

#pragma unroll
      for (int kt = 0; kt < 4; ++kt) {                // input 0: h0[s]
        const int unit = (kh * 16 + kt * 4 + kg) * 32 + mh * 16 + lrow;
        short8 ahi = as_short8(p0h[unit]);
        short8 alo = as_short8(p0l[unit]);
#pragma unroll
        for (int n = 0; n < 4; ++n) {
          acc[n] = mfma16(ahi, Bhi[0][kt][n], acc[n]);
          acc[n] = mfma16(alo, Bhi[0][kt][n], acc[n]);
          acc[n] = mfma16(ahi, Blo[0][kt][n], acc[n]);
        }
      }
#pragma unroll
      for (int kt = 0; kt < 4; ++kt) {                // input 1: h1[s-1]
        short8 ahi = as_short8(a1h[kt]);
        short8 alo = as_short8(a1l[kt]);
#pragma unroll
        for (int n = 0; n < 4; ++n) {
          acc[n] = mfma16(ahi, Bhi[1][kt][n], acc[n]);
          acc[n] = mfma16(alo, Bhi[1][kt][n], acc[n]);
          acc[n] = mfma16(ahi, Blo[1][kt][n], acc[n]);
        }
      }

      if (kh == 1) {
#pragma unroll
        for (int n = 0; n < 4; ++n) pg[mh][n][lane] = acc[n];
      }
      __syncthreads();
      if (kh == 0) {
#pragma unroll
        for (int n = 0; n < 4; ++n) acc[n] += pg[mh][n][lane];
        unsigned short* sh = (unsigned short*)(h1p + ((s & 1) ? pl10 : pl00));
        unsigned short* sl = (unsigned short*)(h1p + ((s & 1) ? pl11 : pl01));
        float hva[4];
#pragma unroll
        for (int r = 0; r < 4; ++r) {
          float gi = acc[0][r] + bias[0];
          float gf = acc[1][r] + bias[1];
          float gg = acc[2][r] + bias[2];
          float go = acc[3][r] + bias[3];
          float cc = sigf(gf) * cst[r] + sigf(gi) * tanh_fast(gg);
          cst[r] = cc;
          float hv = sigf(go) * tanh_fast(cc);
          hva[r] = hv;
          const int b = mh * 16 + kg * 4 + r;
          unsigned short hh = f2bf(hv);
          unsigned short hl = f2bf(hv - bf2f(hh));
          sh[(kcS * 32 + b) * 8 + foS] = hh;
          sl[(kcS * 32 + b) * 8 + foS] = hl;
        }
        __threadfence();
        if (lane == 0)
          __hip_atomic_fetch_add(flag1, 1u, __ATOMIC_RELEASE,
                                 __HIP_MEMORY_SCOPE_AGENT);
        if (s == TT - 1) {
          // out[b] = sum_f h1[b,f] * Whead[f] + b_head
#pragma unroll
          for (int r = 0; r < 4; ++r) {
            float v = hva[r] * wh;
            v += __shfl_xor(v, 1);
            v += __shfl_xor(v, 2);
            v += __shfl_xor(v, 4);
            v += __shfl_xor(v, 8);
            if (lrow == 0) {
              float add = v + (fs == 0 ? bh : 0.0f);
              atomicAdd(out + bg * 32 + mh * 16 + kg * 4 + r, add);
            }
          }
        }
      }
      __syncthreads();
    }
  }
}

extern "C" void kernel_launch(void* const* d_in, const int* in_sizes, int n_in,
                              void* d_out, int out_size, void* d_ws, size_t ws_size,
                              hipStream_t stream) {
  (void)in_sizes; (void)n_in; (void)ws_size;
  const float* x     = (const float*)d_in[0];
  const float* Wih0  = (const float*)d_in[1];
  const float* Whh0  = (const float*)d_in[2];
  const float* bih0  = (const float*)d_in[3];
  const float* bhh0  = (const float*)d_in[4];
  const float* Wih1  = (const float*)d_in[5];
  const float* Whh1  = (const float*)d_in[6];
  const float* bih1  = (const float*)d_in[7];
  const float* bhh1  = (const float*)d_in[8];
  const float* Whead = (const float*)d_in[9];
  const float* bhead = (const float*)d_in[10];

  hipMemsetAsync(d_ws, 0, WS_BYTES, stream);                 // h bufs + flags
  hipMemsetAsync(d_out, 0, (size_t)out_size * sizeof(float), stream);
  lstm2_kernel<<<dim3(256), dim3(256), 0, stream>>>(
      x, Wih0, Whh0, bih0, bhh0, Wih1, Whh1, bih1, bhh1, Whead, bhead,
      (float*)d_out, (uint8_t*)d_ws);
}

// Round 5
// 4406.307 us; speedup vs baseline: 4.9342x; 4.9342x over previous
//
#include <hip/hip_runtime.h>
#include <stdint.h>

// ---------------------------------------------------------------------------
// 2-layer LSTM (B=256, T=512, IN=64, H=256) + linear head, persistent kernel.
//
// Grid 256 x 256 threads. bg = bid&7 (batch group of 32), role = bid>>3:
//   role 0..15  -> layer-0 block, feature slice role&15 (16 h-features)
//   role 16..31 -> layer-1 block, feature slice role&15
// Weights live in VGPRs as MFMA B-fragments, hi/lo bf16 split for ~fp32
// matmul accuracy: gates = Whi@hhi + Whi@hlo + Wlo@hhi.
//
// ROUND-4 CHANGE (from 21.4ms profile: MfmaUtil 1.2%, 42us/step => agent
// acquire/release fences were doing full-L2 wbl2/inv walks every step):
// all cross-block communication now goes through the chip coherence point
// (Infinity Cache) via RELAXED agent-scope atomics (sc0|sc1 loads/stores,
// NO cache-maintenance instructions). Producer h stores are transposed
// through LDS so the global write-through is dword-dense; one flag add per
// block per step (targets = 16/step). Correct for ANY block->XCD mapping.
// ---------------------------------------------------------------------------

#define TT 512

typedef short short8 __attribute__((ext_vector_type(8)));
typedef float f32x4 __attribute__((ext_vector_type(4)));

#define H0_OFF   0
#define H1_OFF   524288      // 2 bufs * 8 bg * 2 comp * 1024 units * 16B
#define FLAGS_OFF 1048576
#define WS_BYTES (1048576 + 4096)

static __device__ __forceinline__ unsigned short f2bf(float f) {
  uint32_t u = __float_as_uint(f);
  u += 0x7fffu + ((u >> 16) & 1u);          // round-to-nearest-even
  return (unsigned short)(u >> 16);
}
static __device__ __forceinline__ float bf2f(unsigned short b) {
  return __uint_as_float(((uint32_t)b) << 16);
}

static __device__ __forceinline__ void pack_hilo(float4 a, float4 b,
                                                 short8& hi, short8& lo) {
  float v[8] = {a.x, a.y, a.z, a.w, b.x, b.y, b.z, b.w};
#pragma unroll
  for (int i = 0; i < 8; ++i) {
    unsigned short h = f2bf(v[i]);
    hi[i] = (short)h;
    lo[i] = (short)f2bf(v[i] - bf2f(h));
  }
}

static __device__ __forceinline__ float sigf(float x) {
  return 1.0f / (1.0f + __expf(-x));
}
static __device__ __forceinline__ float tanh_fast(float x) {
  float xx = fminf(fmaxf(x, -15.0f), 15.0f);
  float e = __expf(2.0f * xx);
  return (e - 1.0f) / (e + 1.0f);
}

static __device__ __forceinline__ f32x4 mfma16(short8 a, short8 b, f32x4 c) {
  return __builtin_amdgcn_mfma_f32_16x16x32_bf16(a, b, c, 0, 0, 0);
}

// relaxed agent-scope load/store: L1/L2-bypassing, NO cache maintenance
static __device__ __forceinline__ uint32_t ld_sc(const uint32_t* p) {
  return __hip_atomic_load(p, __ATOMIC_RELAXED, __HIP_MEMORY_SCOPE_AGENT);
}
static __device__ __forceinline__ void st_sc(uint32_t* p, uint32_t v) {
  __hip_atomic_store(p, v, __ATOMIC_RELAXED, __HIP_MEMORY_SCOPE_AGENT);
}

// read one 16B A-fragment from the coherence point
static __device__ __forceinline__ short8 load_unit(const uint32_t* p) {
  union { uint32_t u[4]; short8 s; } c;
  c.u[0] = ld_sc(p + 0);
  c.u[1] = ld_sc(p + 1);
  c.u[2] = ld_sc(p + 2);
  c.u[3] = ld_sc(p + 3);
  return c.s;
}

// all lanes spin on a wave-uniform flag value; relaxed (no cache maintenance)
static __device__ __forceinline__ void spin_ge(uint32_t* f, uint32_t tgt) {
  asm volatile("" ::: "memory");
  int guard = 0;
  while (__hip_atomic_load(f, __ATOMIC_RELAXED, __HIP_MEMORY_SCOPE_AGENT) < tgt) {
    __builtin_amdgcn_s_sleep(1);
    if (++guard > (1 << 24)) break;         // safety escape: corrupt, not hang
  }
  asm volatile("" ::: "memory");
}

__global__ __launch_bounds__(256, 1) void lstm2_kernel(
    const float* __restrict__ x,
    const float* __restrict__ Wih0, const float* __restrict__ Whh0,
    const float* __restrict__ bih0, const float* __restrict__ bhh0,
    const float* __restrict__ Wih1, const float* __restrict__ Whh1,
    const float* __restrict__ bih1, const float* __restrict__ bhh1,
    const float* __restrict__ Whead, const float* __restrict__ bhead,
    float* __restrict__ out, uint8_t* __restrict__ ws)
{
  const int bid   = blockIdx.x;
  const int bg    = bid & 7;          // batch group of 32 rows
  const int role  = bid >> 3;
  const int layer = role >> 4;        // 0 or 1
  const int fs    = role & 15;        // feature slice (16 features)
  const int f0    = fs << 4;
  const int tid   = threadIdx.x;
  const int wave  = tid >> 6;
  const int lane  = tid & 63;
  const int mh    = (wave >> 1) & 1;  // M half (batch rows mh*16..+16)
  const int kh    = wave & 1;         // K half
  const int lrow  = lane & 15;
  const int kg    = lane >> 4;        // 0..3

  uint32_t* h0d = (uint32_t*)(ws + H0_OFF);
  uint32_t* h1d = (uint32_t*)(ws + H1_OFF);
  uint32_t* flags = (uint32_t*)(ws + FLAGS_OFF);
  uint32_t* flag0 = flags + bg * 128;
  uint32_t* flag1 = flags + bg * 128 + 64;

  __shared__ f32x4 pg[2][4][64];      // cross-kh partial gates exchange (8KB)
  __shared__ uint32_t hbuf[32][16];   // row-major h transpose buf (2KB)
                                      // hbuf[row][feat] = hh | (hl<<16)

  // --------------------------- weight prep ---------------------------------
  // B-frag: col c = n*16 + lrow  ->  weight row R = n*256 + f0 + lrow
  //         k = kh*128 + kt*32 + kg*8   (K=256 matrices)
  short8 Bhi[2][4][4], Blo[2][4][4];  // [input][kt][n]; input1 = W_hh
  short8 Xhi[4], Xlo[4];              // layer-0 W_ih (K=64): k = kh*32+kg*8
  float bias[4] = {0, 0, 0, 0};
  float wh = 0.0f, bh = 0.0f;

  const float* WH = layer ? Whh1 : Whh0;
  const float* BI = layer ? bih1 : bih0;
  const float* BH = layer ? bhh1 : bhh0;

#pragma unroll
  for (int kt = 0; kt < 4; ++kt) {
#pragma unroll
    for (int n = 0; n < 4; ++n) {
      const int R = n * 256 + f0 + lrow;
      const int k = kh * 128 + kt * 32 + kg * 8;
      const float* p = WH + (size_t)R * 256 + k;
      pack_hilo(*(const float4*)p, *(const float4*)(p + 4),
                Bhi[1][kt][n], Blo[1][kt][n]);
    }
  }
  if (layer == 1) {
#pragma unroll
    for (int kt = 0; kt < 4; ++kt) {
#pragma unroll
      for (int n = 0; n < 4; ++n) {
        const int R = n * 256 + f0 + lrow;
        const int k = kh * 128 + kt * 32 + kg * 8;
        const float* p = Wih1 + (size_t)R * 256 + k;
        pack_hilo(*(const float4*)p, *(const float4*)(p + 4),
                  Bhi[0][kt][n], Blo[0][kt][n]);
      }
    }
  } else {
#pragma unroll
    for (int n = 0; n < 4; ++n) {
      const int R = n * 256 + f0 + lrow;
      const float* p = Wih0 + (size_t)R * 64 + kh * 32 + kg * 8;
      pack_hilo(*(const float4*)p, *(const float4*)(p + 4), Xhi[n], Xlo[n]);
    }
  }
  if (kh == 0) {
#pragma unroll
    for (int n = 0; n < 4; ++n) {
      const int R = n * 256 + f0 + lrow;
      bias[n] = BI[R] + BH[R];
    }
    if (layer == 1) { wh = Whead[f0 + lrow]; bh = bhead[0]; }
  }

  // h fragment planes: (buf, comp) -> 1024 units of 16B; unit = kc*32 + row
  // dword address = (plane + unit)*4
  const size_t pl00 = (size_t)((0 * 8 + bg) * 2 + 0) * 1024;
  const size_t pl01 = (size_t)((0 * 8 + bg) * 2 + 1) * 1024;
  const size_t pl10 = (size_t)((1 * 8 + bg) * 2 + 0) * 1024;
  const size_t pl11 = (size_t)((1 * 8 + bg) * 2 + 1) * 1024;

  // cooperative-store decomposition: 512 dwords/step, 2 per thread
  // entry e: p = e>>8 (hi/lo plane), u_local = (e&255)>>2, j = e&3
  // row = u_local & 31, kcL = u_local >> 5, feats c = kcL*8 + j*2
  const int e0 = tid * 2;

  float cst[4] = {0, 0, 0, 0};

  if (layer == 0) {
    // ------------------------------ layer 0 --------------------------------
    const float* xbase =
        x + (size_t)(bg * 32 + mh * 16 + lrow) * TT * 64 + kh * 32 + kg * 8;
    for (int t = 0; t < TT; ++t) {
      // x contribution first (independent of peers)
      float4 xa = *(const float4*)(xbase + (size_t)t * 64);
      float4 xb = *(const float4*)(xbase + (size_t)t * 64 + 4);
      short8 xhi, xlo;
      pack_hilo(xa, xb, xhi, xlo);

      f32x4 acc[4];
#pragma unroll
      for (int n = 0; n < 4; ++n) {
        acc[n] = (f32x4)(0.0f);
        acc[n] = mfma16(xhi, Xhi[n], acc[n]);
        acc[n] = mfma16(xlo, Xhi[n], acc[n]);
        acc[n] = mfma16(xhi, Xlo[n], acc[n]);
      }

      if (t > 0) spin_ge(flag0, 16u * (uint32_t)t);   // h0[t-1] ready
      const uint32_t* phd = h0d + (((t - 1) & 1) ? pl10 : pl00) * 4;
      const uint32_t* pld = h0d + (((t - 1) & 1) ? pl11 : pl01) * 4;
#pragma unroll
      for (int kt = 0; kt < 4; ++kt) {
        const int unit = (kh * 16 + kt * 4 + kg) * 32 + mh * 16 + lrow;
        short8 ahi = load_unit(phd + unit * 4);
        short8 alo = load_unit(pld + unit * 4);
#pragma unroll
        for (int n = 0; n < 4; ++n) {
          acc[n] = mfma16(ahi, Bhi[1][kt][n], acc[n]);
          acc[n] = mfma16(alo, Bhi[1][kt][n], acc[n]);
          acc[n] = mfma16(ahi, Blo[1][kt][n], acc[n]);
        }
      }

      if (kh == 1) {
#pragma unroll
        for (int n = 0; n < 4; ++n) pg[mh][n][lane] = acc[n];
      }
      __syncthreads();
      if (kh == 0) {
#pragma unroll
        for (int n = 0; n < 4; ++n) acc[n] += pg[mh][n][lane];
#pragma unroll
        for (int r = 0; r < 4; ++r) {
          float gi = acc[0][r] + bias[0];
          float gf = acc[1][r] + bias[1];
          float gg = acc[2][r] + bias[2];
          float go = acc[3][r] + bias[3];
          float cc = sigf(gf) * cst[r] + sigf(gi) * tanh_fast(gg);
          cst[r] = cc;
          float hv = sigf(go) * tanh_fast(cc);
          const int b = mh * 16 + kg * 4 + r;
          unsigned short hh = f2bf(hv);
          unsigned short hl = f2bf(hv - bf2f(hh));
          hbuf[b][lrow] = (uint32_t)hh | ((uint32_t)hl << 16);
        }
      }
      __syncthreads();                          // hbuf ready
      // backpressure: L1 must have consumed h0[t-2] before we overwrite
      if (t > 1) spin_ge(flag1, 16u * (uint32_t)(t - 1));
      {
        uint32_t* dsth = h0d + ((t & 1) ? pl10 : pl00) * 4;
        uint32_t* dstl = h0d + ((t & 1) ? pl11 : pl01) * 4;
#pragma unroll
        for (int ee = 0; ee < 2; ++ee) {
          const int e = e0 + ee;
          const int p = e >> 8;
          const int ul = (e & 255) >> 2;
          const int j = e & 3;
          const int row = ul & 31;
          const int c = (ul >> 5) * 8 + j * 2;
          const uint32_t w0 = hbuf[row][c], w1 = hbuf[row][c + 1];
          const uint32_t val = p == 0
              ? ((w0 & 0xffffu) | (w1 << 16))
              : ((w0 >> 16) | (w1 & 0xffff0000u));
          const int ug = (fs * 2 + (ul >> 5)) * 32 + row;
          st_sc((p == 0 ? dsth : dstl) + ug * 4 + j, val);
        }
      }
      __syncthreads();                          // drains vmcnt: stores done
      asm volatile("" ::: "memory");
      if (tid == 0)
        __hip_atomic_fetch_add(flag0, 1u, __ATOMIC_RELAXED,
                               __HIP_MEMORY_SCOPE_AGENT);
    }
  } else {
    // ------------------------------ layer 1 --------------------------------
    for (int s = 0; s < TT; ++s) {
      if (s > 0) spin_ge(flag1, 16u * (uint32_t)s);   // h1[s-1] ready (peers)
      const uint32_t* p1h = h1d + (((s - 1) & 1) ? pl10 : pl00) * 4;
      const uint32_t* p1l = h1d + (((s - 1) & 1) ? pl11 : pl01) * 4;
      short8 a1h[4], a1l[4];
#pragma unroll
      for (int kt = 0; kt < 4; ++kt) {
        const int unit = (kh * 16 + kt * 4 + kg) * 32 + mh * 16 + lrow;
        a1h[kt] = load_unit(p1h + unit * 4);
        a1l[kt] = load_unit(p1l + unit * 4);
      }

      spin_ge(flag0, 16u * (uint32_t)(s + 1));        // h0[s] ready
      const uint32_t* p0h = h0d + ((s & 1) ? pl10 : pl00) * 4;
      const uint32_t* p0l = h0d + ((s & 1) ? pl11 : pl01) * 4;

      f32x4 acc[4];
#pragma unroll
      for (int n = 0; n < 4; ++n) acc[n] = (f32x4)(0.0f);

#pragma unroll
      for (int kt = 0; kt < 4; ++kt) {                // input 0: h0[s]
        const int unit = (kh * 16 + kt * 4 + kg) * 32 + mh * 16 + lrow;
        short8 ahi = load_unit(p0h + unit * 4);
        short8 alo = load_unit(p0l + unit * 4);
#pragma unroll
        for (int n = 0; n < 4; ++n) {
          acc[n] = mfma16(ahi, Bhi[0][kt][n], acc[n]);
          acc[n] = mfma16(alo, Bhi[0][kt][n], acc[n]);
          acc[n] = mfma16(ahi, Blo[0][kt][n], acc[n]);
        }
      }
#pragma unroll
      for (int kt = 0; kt < 4; ++kt) {                // input 1: h1[s-1]
#pragma unroll
        for (int n = 0; n < 4; ++n) {
          acc[n] = mfma16(a1h[kt], Bhi[1][kt][n], acc[n]);
          acc[n] = mfma16(a1l[kt], Bhi[1][kt][n], acc[n]);
          acc[n] = mfma16(a1h[kt], Blo[1][kt][n], acc[n]);
        }
      }

      if (kh == 1) {
#pragma unroll
        for (int n = 0; n < 4; ++n) pg[mh][n][lane] = acc[n];
      }
      __syncthreads();
      if (kh == 0) {
#pragma unroll
        for (int n = 0; n < 4; ++n) acc[n] += pg[mh][n][lane];
        float hva[4];
#pragma unroll
        for (int r = 0; r < 4; ++r) {
          float gi = acc[0][r] + bias[0];
          float gf = acc[1][r] + bias[1];
          float gg = acc[2][r] + bias[2];
          float go = acc[3][r] + bias[3];
          float cc = sigf(gf) * cst[r] + sigf(gi) * tanh_fast(gg);
          cst[r] = cc;
          float hv = sigf(go) * tanh_fast(cc);
          hva[r] = hv;
          const int b = mh * 16 + kg * 4 + r;
          unsigned short hh = f2bf(hv);
          unsigned short hl = f2bf(hv - bf2f(hh));
          hbuf[b][lrow] = (uint32_t)hh | ((uint32_t)hl << 16);
        }
        if (s == TT - 1) {
          // out[b] = sum_f h1[b,f] * Whead[f] + b_head
#pragma unroll
          for (int r = 0; r < 4; ++r) {
            float v = hva[r] * wh;
            v += __shfl_xor(v, 1);
            v += __shfl_xor(v, 2);
            v += __shfl_xor(v, 4);
            v += __shfl_xor(v, 8);
            if (lrow == 0) {
              float add = v + (fs == 0 ? bh : 0.0f);
              atomicAdd(out + bg * 32 + mh * 16 + kg * 4 + r, add);
            }
          }
        }
      }
      __syncthreads();                          // hbuf ready
      {
        uint32_t* dsth = h1d + ((s & 1) ? pl10 : pl00) * 4;
        uint32_t* dstl = h1d + ((s & 1) ? pl11 : pl01) * 4;
#pragma unroll
        for (int ee = 0; ee < 2; ++ee) {
          const int e = e0 + ee;
          const int p = e >> 8;
          const int ul = (e & 255) >> 2;
          const int j = e & 3;
          const int row = ul & 31;
          const int c = (ul >> 5) * 8 + j * 2;
          const uint32_t w0 = hbuf[row][c], w1 = hbuf[row][c + 1];
          const uint32_t val = p == 0
              ? ((w0 & 0xffffu) | (w1 << 16))
              : ((w0 >> 16) | (w1 & 0xffff0000u));
          const int ug = (fs * 2 + (ul >> 5)) * 32 + row;
          st_sc((p == 0 ? dsth : dstl) + ug * 4 + j, val);
        }
      }
      __syncthreads();                          // drains vmcnt: stores done
      asm volatile("" ::: "memory");
      if (tid == 0)
        __hip_atomic_fetch_add(flag1, 1u, __ATOMIC_RELAXED,
                               __HIP_MEMORY_SCOPE_AGENT);
    }
  }
}

extern "C" void kernel_launch(void* const* d_in, const int* in_sizes, int n_in,
                              void* d_out, int out_size, void* d_ws, size_t ws_size,
                              hipStream_t stream) {
  (void)in_sizes; (void)n_in; (void)ws_size;
  const float* x     = (const float*)d_in[0];
  const float* Wih0  = (const float*)d_in[1];
  const float* Whh0  = (const float*)d_in[2];
  const float* bih0  = (const float*)d_in[3];
  const float* bhh0  = (const float*)d_in[4];
  const float* Wih1  = (const float*)d_in[5];
  const float* Whh1  = (const float*)d_in[6];
  const float* bih1  = (const float*)d_in[7];
  const float* bhh1  = (const float*)d_in[8];
  const float* Whead = (const float*)d_in[9];
  const float* bhead = (const float*)d_in[10];

  hipMemsetAsync(d_ws, 0, WS_BYTES, stream);                 // h bufs + flags
  hipMemsetAsync(d_out, 0, (size_t)out_size * sizeof(float), stream);
  lstm2_kernel<<<dim3(256), dim3(256), 0, stream>>>(
      x, Wih0, Whh0, bih0, bhh0, Wih1, Whh1, bih1, bhh1, Whead, bhead,
      (float*)d_out, (uint8_t*)d_ws);
}

// Round 7
// 3002.833 us; speedup vs baseline: 7.2403x; 1.4674x over previous
//
#include <hip/hip_runtime.h>
#include <stdint.h>

// ---------------------------------------------------------------------------
// 2-layer LSTM (B=256, T=512, IN=64, H=256) + linear head, persistent kernel.
//
// Grid 256 x 256 threads. bg = bid&7 (batch group of 32), role = bid>>3:
//   role 0..15  -> layer-0 block, feature slice role&15 (16 h-features)
//   role 16..31 -> layer-1 block, feature slice role&15
// Weights live in VGPRs as MFMA B-fragments, hi/lo bf16 split:
// gates = Whi@hhi + Whi@hlo + Wlo@hhi.
//
// ROUND-6 CHANGES (from 4.4ms profile: MfmaUtil 6%, ~17k cyc/step of MALL
// latency; suspects = flag fetch_add convoy + 64 scalar atomic h-loads):
//  * store-only flags: producer i stores step count to flags[i]; consumers
//    poll 16 slots with ONE coalesced load + __all().  No RMW anywhere.
//  * h exchange via inline-asm global_load_dwordx4 / global_store_dwordx2
//    with sc0 sc1 (same coherence as before, 4x fewer ops), explicit
//    vmcnt(0) + sched_barrier(0) before use (rule: compiler may hoist
//    reg-only MFMA past asm waits).
//  * h0 ring deepened to 4 slots (L0 can run 3 steps ahead of L1).
//  * hbuf padded [32][17] (kill 4-way transpose bank conflict).
// ---------------------------------------------------------------------------

#define TT 512

typedef short short8 __attribute__((ext_vector_type(8)));
typedef float f32x4 __attribute__((ext_vector_type(4)));
typedef uint32_t u32x4 __attribute__((ext_vector_type(4)));
typedef uint32_t u32x2 __attribute__((ext_vector_type(2)));

// ws layout (dword planes of 4096 = 16KB each: 32 rows x 256 feats bf16):
//   h0: 4 slots x 8 bg x 2 comp  = 1 MB      plane((slot*8+bg)*2+comp)
//   h1: 2 slots x 8 bg x 2 comp  = 512 KB
//   flags: per bg: [0..15]=L0 slots, [16..31]=L1 slots (two 64B lines)
#define H0_OFF    0
#define H1_OFF    1048576
#define FLAGS_OFF 1572864
#define WS_BYTES  (1572864 + 4096)

static __device__ __forceinline__ unsigned short f2bf(float f) {
  uint32_t u = __float_as_uint(f);
  u += 0x7fffu + ((u >> 16) & 1u);          // round-to-nearest-even
  return (unsigned short)(u >> 16);
}
static __device__ __forceinline__ float bf2f(unsigned short b) {
  return __uint_as_float(((uint32_t)b) << 16);
}

static __device__ __forceinline__ void pack_hilo(float4 a, float4 b,
                                                 short8& hi, short8& lo) {
  float v[8] = {a.x, a.y, a.z, a.w, b.x, b.y, b.z, b.w};
#pragma unroll
  for (int i = 0; i < 8; ++i) {
    unsigned short h = f2bf(v[i]);
    hi[i] = (short)h;
    lo[i] = (short)f2bf(v[i] - bf2f(h));
  }
}

static __device__ __forceinline__ float sigf(float x) {
  return 1.0f / (1.0f + __expf(-x));
}
static __device__ __forceinline__ float tanh_fast(float x) {
  float xx = fminf(fmaxf(x, -15.0f), 15.0f);
  float e = __expf(2.0f * xx);
  return (e - 1.0f) / (e + 1.0f);
}

static __device__ __forceinline__ f32x4 mfma16(short8 a, short8 b, f32x4 c) {
  return __builtin_amdgcn_mfma_f32_16x16x32_bf16(a, b, c, 0, 0, 0);
}

static __device__ __forceinline__ short8 u2s8(u32x4 v) {
  union { u32x4 u; short8 s; } c; c.u = v; return c.s;
}

// coherent (L1/L2-bypassing) vector ops — data-race-free by flag protocol
static __device__ __forceinline__ u32x4 ldx4_cc(const uint32_t* p) {
  u32x4 r;
  asm volatile("global_load_dwordx4 %0, %1, off sc0 sc1"
               : "=&v"(r) : "v"(p) : "memory");
  return r;
}
static __device__ __forceinline__ void stx2_cc(uint32_t* p, u32x2 v) {
  asm volatile("global_store_dwordx2 %0, %1, off sc0 sc1"
               :: "v"(p), "v"(v) : "memory");
}
static __device__ __forceinline__ void vm_drain() {
  asm volatile("s_waitcnt vmcnt(0)" ::: "memory");
}

// poll 16 per-producer slots with one coalesced load; exit when all >= tgt
static __device__ __forceinline__ void wait_flags(const uint32_t* fl,
                                                  uint32_t tgt) {
  const uint32_t* p = fl + (threadIdx.x & 15);
  int guard = 0;
  for (;;) {
    uint32_t v = __hip_atomic_load(p, __ATOMIC_RELAXED,
                                   __HIP_MEMORY_SCOPE_AGENT);
    if (__all((int)(v >= tgt))) break;
    if (++guard > (1 << 20)) break;         // safety escape: corrupt, not hang
  }
}

__global__ __launch_bounds__(256, 1) void lstm2_kernel(
    const float* __restrict__ x,
    const float* __restrict__ Wih0, const float* __restrict__ Whh0,
    const float* __restrict__ bih0, const float* __restrict__ bhh0,
    const float* __restrict__ Wih1, const float* __restrict__ Whh1,
    const float* __restrict__ bih1, const float* __restrict__ bhh1,
    const float* __restrict__ Whead, const float* __restrict__ bhead,
    float* __restrict__ out, uint8_t* __restrict__ ws)
{
  const int bid   = blockIdx.x;
  const int bg    = bid & 7;          // batch group of 32 rows
  const int role  = bid >> 3;
  const int layer = role >> 4;        // 0 or 1
  const int fs    = role & 15;        // feature slice (16 features)
  const int f0    = fs << 4;
  const int tid   = threadIdx.x;
  const int wave  = tid >> 6;
  const int lane  = tid & 63;
  const int mh    = (wave >> 1) & 1;  // M half (batch rows mh*16..+16)
  const int kh    = wave & 1;         // K half
  const int lrow  = lane & 15;
  const int kg    = lane >> 4;        // 0..3

  uint32_t* h0d = (uint32_t*)(ws + H0_OFF);
  uint32_t* h1d = (uint32_t*)(ws + H1_OFF);
  uint32_t* flags  = (uint32_t*)(ws + FLAGS_OFF);
  uint32_t* flags0 = flags + bg * 32;
  uint32_t* flags1 = flags + bg * 32 + 16;

  __shared__ f32x4 pg[2][4][64];      // cross-kh partial gates exchange (8KB)
  __shared__ uint32_t hbuf[32][17];   // padded transpose buf (conflict-free reads)

  // --------------------------- weight prep ---------------------------------
  short8 Bhi[2][4][4], Blo[2][4][4];  // [input][kt][n]; input1 = W_hh
  short8 Xhi[4], Xlo[4];              // layer-0 W_ih (K=64)
  float bias[4] = {0, 0, 0, 0};
  float wh = 0.0f, bh = 0.0f;

  const float* WH = layer ? Whh1 : Whh0;
  const float* BI = layer ? bih1 : bih0;
  const float* BH = layer ? bhh1 : bhh0;

#pragma unroll
  for (int kt = 0; kt < 4; ++kt) {
#pragma unroll
    for (int n = 0; n < 4; ++n) {
      const int R = n * 256 + f0 + lrow;
      const int k = kh * 128 + kt * 32 + kg * 8;
      const float* p = WH + (size_t)R * 256 + k;
      pack_hilo(*(const float4*)p, *(const float4*)(p + 4),
                Bhi[1][kt][n], Blo[1][kt][n]);
    }
  }
  if (layer == 1) {
#pragma unroll
    for (int kt = 0; kt < 4; ++kt) {
#pragma unroll
      for (int n = 0; n < 4; ++n) {
        const int R = n * 256 + f0 + lrow;
        const int k = kh * 128 + kt * 32 + kg * 8;
        const float* p = Wih1 + (size_t)R * 256 + k;
        pack_hilo(*(const float4*)p, *(const float4*)(p + 4),
                  Bhi[0][kt][n], Blo[0][kt][n]);
      }
    }
  } else {
#pragma unroll
    for (int n = 0; n < 4; ++n) {
      const int R = n * 256 + f0 + lrow;
      const float* p = Wih0 + (size_t)R * 64 + kh * 32 + kg * 8;
      pack_hilo(*(const float4*)p, *(const float4*)(p + 4), Xhi[n], Xlo[n]);
    }
  }
  if (kh == 0) {
#pragma unroll
    for (int n = 0; n < 4; ++n) {
      const int R = n * 256 + f0 + lrow;
      bias[n] = BI[R] + BH[R];
    }
    if (layer == 1) { wh = Whead[f0 + lrow]; bh = bhead[0]; }
  }

  // cooperative-store decomposition: 256 hi-dwords + 256 lo-dwords per step;
  // thread -> one dwordx2 (j0, j0+1) of one (plane, unit)
  const int e0s  = tid * 2;
  const int pp   = e0s >> 8;          // 0 = hi plane, 1 = lo plane
  const int uls  = (e0s & 255) >> 2;  // local unit 0..63
  const int sj0  = e0s & 3;           // dword 0 or 2
  const int srow = uls & 31;
  const int skc  = uls >> 5;
  const int scc  = skc * 8 + sj0 * 2;
  const int sug  = (fs * 2 + skc) * 32 + srow;   // global unit index

  float cst[4] = {0, 0, 0, 0};

  if (layer == 0) {
    // ------------------------------ layer 0 --------------------------------
    const float* xbase =
        x + (size_t)(bg * 32 + mh * 16 + lrow) * TT * 64 + kh * 32 + kg * 8;
    for (int t = 0; t < TT; ++t) {
      // x contribution first (independent of peers)
      float4 xa = *(const float4*)(xbase + (size_t)t * 64);
      float4 xb = *(const float4*)(xbase + (size_t)t * 64 + 4);
      short8 xhi, xlo;
      pack_hilo(xa, xb, xhi, xlo);

      f32x4 acc[4];
#pragma unroll
      for (int n = 0; n < 4; ++n) {
        acc[n] = (f32x4)(0.0f);
        acc[n] = mfma16(xhi, Xhi[n], acc[n]);
        acc[n] = mfma16(xlo, Xhi[n], acc[n]);
        acc[n] = mfma16(xhi, Xlo[n], acc[n]);
      }

      if (t > 0) wait_flags(flags0, (uint32_t)t);     // h0[t-1] ready
      {
        const uint32_t* base =
            h0d + (size_t)((((t - 1) & 3) * 8 + bg) * 2) * 4096;
        u32x4 vh[4], vl[4];
#pragma unroll
        for (int kt = 0; kt < 4; ++kt) {
          const int unit = (kh * 16 + kt * 4 + kg) * 32 + mh * 16 + lrow;
          vh[kt] = ldx4_cc(base + unit * 4);
          vl[kt] = ldx4_cc(base + 4096 + unit * 4);
        }
        vm_drain();
        __builtin_amdgcn_sched_barrier(0);
#pragma unroll
        for (int kt = 0; kt < 4; ++kt) {
          short8 ahi = u2s8(vh[kt]);
          short8 alo = u2s8(vl[kt]);
#pragma unroll
          for (int n = 0; n < 4; ++n) {
            acc[n] = mfma16(ahi, Bhi[1][kt][n], acc[n]);
            acc[n] = mfma16(alo, Bhi[1][kt][n], acc[n]);
            acc[n] = mfma16(ahi, Blo[1][kt][n], acc[n]);
          }
        }
      }

      if (kh == 1) {
#pragma unroll
        for (int n = 0; n < 4; ++n) pg[mh][n][lane] = acc[n];
      }
      __syncthreads();
      if (kh == 0) {
#pragma unroll
        for (int n = 0; n < 4; ++n) acc[n] += pg[mh][n][lane];
#pragma unroll
        for (int r = 0; r < 4; ++r) {
          float gi = acc[0][r] + bias[0];
          float gf = acc[1][r] + bias[1];
          float gg = acc[2][r] + bias[2];
          float go = acc[3][r] + bias[3];
          float cc = sigf(gf) * cst[r] + sigf(gi) * tanh_fast(gg);
          cst[r] = cc;
          float hv = sigf(go) * tanh_fast(cc);
          const int b = mh * 16 + kg * 4 + r;
          unsigned short hh = f2bf(hv);
          unsigned short hl = f2bf(hv - bf2f(hh));
          hbuf[b][lrow] = (uint32_t)hh | ((uint32_t)hl << 16);
        }
      }
      __syncthreads();                          // hbuf ready
      // backpressure: ring-4 slot t&3 holds h0[t-4]; L1 must have finished
      // step t-4, i.e. all flags1 >= t-3
      if (t >= 4) wait_flags(flags1, (uint32_t)(t - 3));
      {
        uint32_t* base = h0d + (size_t)(((t & 3) * 8 + bg) * 2) * 4096;
        uint32_t* dstp = (pp == 0) ? base : base + 4096;
        uint32_t w0 = hbuf[srow][scc],     w1 = hbuf[srow][scc + 1];
        uint32_t w2 = hbuf[srow][scc + 2], w3 = hbuf[srow][scc + 3];
        u32x2 val;
        if (pp == 0) {
          val[0] = (w0 & 0xffffu) | (w1 << 16);
          val[1] = (w2 & 0xffffu) | (w3 << 16);
        } else {
          val[0] = (w0 >> 16) | (w1 & 0xffff0000u);
          val[1] = (w2 >> 16) | (w3 & 0xffff0000u);
        }
        stx2_cc(dstp + sug * 4 + sj0, val);
      }
      vm_drain();                               // h stores at coherence point
      __syncthreads();
      if (tid == 0)
        __hip_atomic_store(flags0 + fs, (uint32_t)(t + 1), __ATOMIC_RELAXED,
                           __HIP_MEMORY_SCOPE_AGENT);
    }
  } else {
    // ------------------------------ layer 1 --------------------------------
    for (int s = 0; s < TT; ++s) {
      if (s > 0) wait_flags(flags1, (uint32_t)s);     // h1[s-1] ready (peers)
      const uint32_t* b1 =
          h1d + (size_t)((((s - 1) & 1) * 8 + bg) * 2) * 4096;
      u32x4 y1h[4], y1l[4];
#pragma unroll
      for (int kt = 0; kt < 4; ++kt) {
        const int unit = (kh * 16 + kt * 4 + kg) * 32 + mh * 16 + lrow;
        y1h[kt] = ldx4_cc(b1 + unit * 4);
        y1l[kt] = ldx4_cc(b1 + 4096 + unit * 4);
      }

      wait_flags(flags0, (uint32_t)(s + 1));          // h0[s] ready
      const uint32_t* b0 = h0d + (size_t)(((s & 3) * 8 + bg) * 2) * 4096;
      u32x4 y0h[4], y0l[4];
#pragma unroll
      for (int kt = 0; kt < 4; ++kt) {
        const int unit = (kh * 16 + kt * 4 + kg) * 32 + mh * 16 + lrow;
        y0h[kt] = ldx4_cc(b0 + unit * 4);
        y0l[kt] = ldx4_cc(b0 + 4096 + unit * 4);
      }
      vm_drain();
      __builtin_amdgcn_sched_barrier(0);

      f32x4 acc[4];
#pragma unroll
      for (int n = 0; n < 4; ++n) acc[n] = (f32x4)(0.0f);

#pragma unroll
      for (int kt = 0; kt < 4; ++kt) {                // input 0: h0[s]
        short8 ahi = u2s8(y0h[kt]);
        short8 alo = u2s8(y0l[kt]);
#pragma unroll
        for (int n = 0; n < 4; ++n) {
          acc[n] = mfma16(ahi, Bhi[0][kt][n], acc[n]);
          acc[n] = mfma16(alo, Bhi[0][kt][n], acc[n]);
          acc[n] = mfma16(ahi, Blo[0][kt][n], acc[n]);
        }
      }
#pragma unroll
      for (int kt = 0; kt < 4; ++kt) {                // input 1: h1[s-1]
        short8 ahi = u2s8(y1h[kt]);
        short8 alo = u2s8(y1l[kt]);
#pragma unroll
        for (int n = 0; n < 4; ++n) {
          acc[n] = mfma16(ahi, Bhi[1][kt][n], acc[n]);
          acc[n] = mfma16(alo, Bhi[1][kt][n], acc[n]);
          acc[n] = mfma16(ahi, Blo[1][kt][n], acc[n]);
        }
      }

      if (kh == 1) {
#pragma unroll
        for (int n = 0; n < 4; ++n) pg[mh][n][lane] = acc[n];
      }
      __syncthreads();
      if (kh == 0) {
#pragma unroll
        for (int n = 0; n < 4; ++n) acc[n] += pg[mh][n][lane];
        float hva[4];
#pragma unroll
        for (int r = 0; r < 4; ++r) {
          float gi = acc[0][r] + bias[0];
          float gf = acc[1][r] + bias[1];
          float gg = acc[2][r] + bias[2];
          float go = acc[3][r] + bias[3];
          float cc = sigf(gf) * cst[r] + sigf(gi) * tanh_fast(gg);
          cst[r] = cc;
          float hv = sigf(go) * tanh_fast(cc);
          hva[r] = hv;
          const int b = mh * 16 + kg * 4 + r;
          unsigned short hh = f2bf(hv);
          unsigned short hl = f2bf(hv - bf2f(hh));
          hbuf[b][lrow] = (uint32_t)hh | ((uint32_t)hl << 16);
        }
        if (s == TT - 1) {
          // out[b] = sum_f h1[b,f] * Whead[f] + b_head
#pragma unroll
          for (int r = 0; r < 4; ++r) {
            float v = hva[r] * wh;
            v += __shfl_xor(v, 1);
            v += __shfl_xor(v, 2);
            v += __shfl_xor(v, 4);
            v += __shfl_xor(v, 8);
            if (lrow == 0) {
              float add = v + (fs == 0 ? bh : 0.0f);
              atomicAdd(out + bg * 32 + mh * 16 + kg * 4 + r, add);
            }
          }
        }
      }
      __syncthreads();                          // hbuf ready
      {
        uint32_t* base = h1d + (size_t)(((s & 1) * 8 + bg) * 2) * 4096;
        uint32_t* dstp = (pp == 0) ? base : base + 4096;
        uint32_t w0 = hbuf[srow][scc],     w1 = hbuf[srow][scc + 1];
        uint32_t w2 = hbuf[srow][scc + 2], w3 = hbuf[srow][scc + 3];
        u32x2 val;
        if (pp == 0) {
          val[0] = (w0 & 0xffffu) | (w1 << 16);
          val[1] = (w2 & 0xffffu) | (w3 << 16);
        } else {
          val[0] = (w0 >> 16) | (w1 & 0xffff0000u);
          val[1] = (w2 >> 16) | (w3 & 0xffff0000u);
        }
        stx2_cc(dstp + sug * 4 + sj0, val);
      }
      vm_drain();                               // h stores at coherence point
      __syncthreads();
      if (tid == 0)
        __hip_atomic_store(flags1 + fs, (uint32_t)(s + 1), __ATOMIC_RELAXED,
                           __HIP_MEMORY_SCOPE_AGENT);
    }
  }
}

extern "C" void kernel_launch(void* const* d_in, const int* in_sizes, int n_in,
                              void* d_out, int out_size, void* d_ws, size_t ws_size,
                              hipStream_t stream) {
  (void)in_sizes; (void)n_in; (void)ws_size;
  const float* x     = (const float*)d_in[0];
  const float* Wih0  = (const float*)d_in[1];
  const float* Whh0  = (const float*)d_in[2];
  const float* bih0  = (const float*)d_in[3];
  const float* bhh0  = (const float*)d_in[4];
  const float* Wih1  = (const float*)d_in[5];
  const float* Whh1  = (const float*)d_in[6];
  const float* bih1  = (const float*)d_in[7];
  const float* bhh1  = (const float*)d_in[8];
  const float* Whead = (const float*)d_in[9];
  const float* bhead = (const float*)d_in[10];

  hipMemsetAsync(d_ws, 0, WS_BYTES, stream);                 // h bufs + flags
  hipMemsetAsync(d_out, 0, (size_t)out_size * sizeof(float), stream);
  lstm2_kernel<<<dim3(256), dim3(256), 0, stream>>>(
      x, Wih0, Whh0, bih0, bhh0, Wih1, Whh1, bih1, bhh1, Whead, bhead,
      (float*)d_out, (uint8_t*)d_ws);
}

// Round 8
// 2883.585 us; speedup vs baseline: 7.5398x; 1.0414x over previous
//
#include <hip/hip_runtime.h>
#include <stdint.h>

// ---------------------------------------------------------------------------
// 2-layer LSTM (B=256, T=512, IN=64, H=256) + linear head, persistent kernel.
//
// Grid 256 x 256 threads. bg = bid&7 (batch group of 32), role = bid>>3:
//   role 0..15  -> layer-0 block, feature slice role&15 (16 h-features)
//   role 16..31 -> layer-1 block, feature slice role&15
// Weights live in VGPRs as MFMA B-fragments, hi/lo bf16 split:
// gates = Whi@hhi + Whi@hlo + Wlo@hhi.  h exchanged via MALL (sc0 sc1).
//
// ROUND-8 CHANGES (from 3.0ms profile: MfmaUtil 8.6%, 14.7k cyc/step vs ~5k
// chain model => poll convoy: 128 waves/group hammering one flag line):
//  * wave0-only polling with s_sleep(2) backoff; __syncthreads release.
//  * per-WAVE release slots (64/layer/bg; lane0 stores after own vm drain)
//    -> no trailing block barrier on the release path.
//  * ONE combined poll per step: lane i dwordx2-loads slots {2i,2i+1} of a
//    128-slot region (flags0[0..64) + flags1[64..128)), per-lane target,
//    __all() -> L1's two sequential flag round trips become one; L0's
//    backpressure merges into its start-of-step wait.
//  * per-bg flag regions 4KB apart (different MALL channels).
//  * counted vmcnt splits: L0 vmcnt(4) hi-MFMAs vmcnt(0) lo-MFMAs;
//    L1 vmcnt(8) h1-MFMAs vmcnt(0) h0-MFMAs (load/compute overlap).
// ---------------------------------------------------------------------------

#define TT 512

typedef short short8 __attribute__((ext_vector_type(8)));
typedef float f32x4 __attribute__((ext_vector_type(4)));
typedef uint32_t u32x4 __attribute__((ext_vector_type(4)));
typedef uint32_t u32x2 __attribute__((ext_vector_type(2)));

// ws layout (dword planes of 4096 = 16KB each: 32 rows x 256 feats bf16):
//   h0: 4 slots x 8 bg x 2 comp  = 1 MB      plane((slot*8+bg)*2+comp)
//   h1: 2 slots x 8 bg x 2 comp  = 512 KB
//   flags: per bg a 4KB region: dwords [0..64)=L0 wave slots,
//          [64..128)=L1 wave slots, rest pad.
#define H0_OFF    0
#define H1_OFF    1048576
#define FLAGS_OFF 1572864
#define WS_BYTES  (1572864 + 8 * 4096)

static __device__ __forceinline__ unsigned short f2bf(float f) {
  uint32_t u = __float_as_uint(f);
  u += 0x7fffu + ((u >> 16) & 1u);          // round-to-nearest-even
  return (unsigned short)(u >> 16);
}
static __device__ __forceinline__ float bf2f(unsigned short b) {
  return __uint_as_float(((uint32_t)b) << 16);
}

static __device__ __forceinline__ void pack_hilo(float4 a, float4 b,
                                                 short8& hi, short8& lo) {
  float v[8] = {a.x, a.y, a.z, a.w, b.x, b.y, b.z, b.w};
#pragma unroll
  for (int i = 0; i < 8; ++i) {
    unsigned short h = f2bf(v[i]);
    hi[i] = (short)h;
    lo[i] = (short)f2bf(v[i] - bf2f(h));
  }
}

static __device__ __forceinline__ float sigf(float x) {
  return 1.0f / (1.0f + __expf(-x));
}
static __device__ __forceinline__ float tanh_fast(float x) {
  float xx = fminf(fmaxf(x, -15.0f), 15.0f);
  float e = __expf(2.0f * xx);
  return (e - 1.0f) / (e + 1.0f);
}

static __device__ __forceinline__ f32x4 mfma16(short8 a, short8 b, f32x4 c) {
  return __builtin_amdgcn_mfma_f32_16x16x32_bf16(a, b, c, 0, 0, 0);
}

static __device__ __forceinline__ short8 u2s8(u32x4 v) {
  union { u32x4 u; short8 s; } c; c.u = v; return c.s;
}

// coherent (cache-bypassing) vector ops — data-race-free by flag protocol
static __device__ __forceinline__ u32x4 ldx4_cc(const uint32_t* p) {
  u32x4 r;
  asm volatile("global_load_dwordx4 %0, %1, off sc0 sc1"
               : "=&v"(r) : "v"(p) : "memory");
  return r;
}
static __device__ __forceinline__ void stx2_cc(uint32_t* p, u32x2 v) {
  asm volatile("global_store_dwordx2 %0, %1, off sc0 sc1"
               :: "v"(p), "v"(v) : "memory");
}
static __device__ __forceinline__ void vm_drain() {
  asm volatile("s_waitcnt vmcnt(0)" ::: "memory");
}
static __device__ __forceinline__ void vm_wait4() {
  asm volatile("s_waitcnt vmcnt(4)" ::: "memory");
}
static __device__ __forceinline__ void vm_wait8() {
  asm volatile("s_waitcnt vmcnt(8)" ::: "memory");
}

// wave0-only combined poll: lane i covers slots {2i,2i+1}; lanes<32 are
// layer-0 slots (target tgt0), lanes>=32 layer-1 slots (target tgt1).
static __device__ __forceinline__ void poll_combined(const uint32_t* fbg,
                                                     uint32_t tgt0,
                                                     uint32_t tgt1,
                                                     int lane) {
  const uint64_t* p = (const uint64_t*)fbg + lane;
  const uint32_t tgt = (lane < 32) ? tgt0 : tgt1;
  int guard = 0;
  for (;;) {
    uint64_t v = __hip_atomic_load(p, __ATOMIC_RELAXED,
                                   __HIP_MEMORY_SCOPE_AGENT);
    uint32_t a = (uint32_t)v, b = (uint32_t)(v >> 32);
    if (__all((int)(a >= tgt && b >= tgt))) break;
    if (++guard > (1 << 20)) break;         // safety escape: corrupt, not hang
    __builtin_amdgcn_s_sleep(2);            // backoff: cut MALL poll pressure
  }
}

__global__ __launch_bounds__(256, 1) void lstm2_kernel(
    const float* __restrict__ x,
    const float* __restrict__ Wih0, const float* __restrict__ Whh0,
    const float* __restrict__ bih0, const float* __restrict__ bhh0,
    const float* __restrict__ Wih1, const float* __restrict__ Whh1,
    const float* __restrict__ bih1, const float* __restrict__ bhh1,
    const float* __restrict__ Whead, const float* __restrict__ bhead,
    float* __restrict__ out, uint8_t* __restrict__ ws)
{
  const int bid   = blockIdx.x;
  const int bg    = bid & 7;          // batch group of 32 rows
  const int role  = bid >> 3;
  const int layer = role >> 4;        // 0 or 1
  const int fs    = role & 15;        // feature slice (16 features)
  const int f0    = fs << 4;
  const int tid   = threadIdx.x;
  const int wave  = tid >> 6;
  const int lane  = tid & 63;
  const int mh    = (wave >> 1) & 1;  // M half (batch rows mh*16..+16)
  const int kh    = wave & 1;         // K half
  const int lrow  = lane & 15;
  const int kg    = lane >> 4;        // 0..3

  uint32_t* h0d = (uint32_t*)(ws + H0_OFF);
  uint32_t* h1d = (uint32_t*)(ws + H1_OFF);
  uint32_t* fbg = (uint32_t*)(ws + FLAGS_OFF) + bg * 1024;  // 4KB region
  uint32_t* my_slot = fbg + (layer ? 64 : 0) + fs * 4 + wave;

  __shared__ f32x4 pg[2][4][64];      // cross-kh partial gates exchange (8KB)
  __shared__ uint32_t hbuf[32][17];   // padded transpose buf

  // --------------------------- weight prep ---------------------------------
  short8 Bhi[2][4][4], Blo[2][4][4];  // [input][kt][n]; input1 = W_hh
  short8 Xhi[4], Xlo[4];              // layer-0 W_ih (K=64)
  float bias[4] = {0, 0, 0, 0};
  float wh = 0.0f, bh = 0.0f;

  const float* WH = layer ? Whh1 : Whh0;
  const float* BI = layer ? bih1 : bih0;
  const float* BH = layer ? bhh1 : bhh0;

#pragma unroll
  for (int kt = 0; kt < 4; ++kt) {
#pragma unroll
    for (int n = 0; n < 4; ++n) {
      const int R = n * 256 + f0 + lrow;
      const int k = kh * 128 + kt * 32 + kg * 8;
      const float* p = WH + (size_t)R * 256 + k;
      pack_hilo(*(const float4*)p, *(const float4*)(p + 4),
                Bhi[1][kt][n], Blo[1][kt][n]);
    }
  }
  if (layer == 1) {
#pragma unroll
    for (int kt = 0; kt < 4; ++kt) {
#pragma unroll
      for (int n = 0; n < 4; ++n) {
        const int R = n * 256 + f0 + lrow;
        const int k = kh * 128 + kt * 32 + kg * 8;
        const float* p = Wih1 + (size_t)R * 256 + k;
        pack_hilo(*(const float4*)p, *(const float4*)(p + 4),
                  Bhi[0][kt][n], Blo[0][kt][n]);
      }
    }
  } else {
#pragma unroll
    for (int n = 0; n < 4; ++n) {
      const int R = n * 256 + f0 + lrow;
      const float* p = Wih0 + (size_t)R * 64 + kh * 32 + kg * 8;
      pack_hilo(*(const float4*)p, *(const float4*)(p + 4), Xhi[n], Xlo[n]);
    }
  }
  if (kh == 0) {
#pragma unroll
    for (int n = 0; n < 4; ++n) {
      const int R = n * 256 + f0 + lrow;
      bias[n] = BI[R] + BH[R];
    }
    if (layer == 1) { wh = Whead[f0 + lrow]; bh = bhead[0]; }
  }

  // cooperative-store decomposition: thread -> one dwordx2 of one (plane,unit)
  const int e0s  = tid * 2;
  const int pp   = e0s >> 8;          // 0 = hi plane, 1 = lo plane
  const int uls  = (e0s & 255) >> 2;  // local unit 0..63
  const int sj0  = e0s & 3;           // dword 0 or 2
  const int srow = uls & 31;
  const int skc  = uls >> 5;
  const int scc  = skc * 8 + sj0 * 2;
  const int sug  = (fs * 2 + skc) * 32 + srow;   // global unit index

  float cst[4] = {0, 0, 0, 0};

  if (layer == 0) {
    // ------------------------------ layer 0 --------------------------------
    const float* xbase =
        x + (size_t)(bg * 32 + mh * 16 + lrow) * TT * 64 + kh * 32 + kg * 8;
    for (int t = 0; t < TT; ++t) {
      // x contribution first (independent of peers)
      float4 xa = *(const float4*)(xbase + (size_t)t * 64);
      float4 xb = *(const float4*)(xbase + (size_t)t * 64 + 4);
      short8 xhi, xlo;
      pack_hilo(xa, xb, xhi, xlo);

      f32x4 acc[4];
#pragma unroll
      for (int n = 0; n < 4; ++n) {
        acc[n] = (f32x4)(0.0f);
        acc[n] = mfma16(xhi, Xhi[n], acc[n]);
        acc[n] = mfma16(xlo, Xhi[n], acc[n]);
        acc[n] = mfma16(xhi, Xlo[n], acc[n]);
      }

      // combined wait: peers done step t-1 (flags0 >= t) AND backpressure
      // (L1 finished step t-4 -> flags1 >= t-3) before this step's store.
      if (t > 0) {
        if (wave == 0)
          poll_combined(fbg, (uint32_t)t,
                        (t >= 4) ? (uint32_t)(t - 3) : 0u, lane);
      }
      __syncthreads();

      {
        const uint32_t* base =
            h0d + (size_t)((((t - 1) & 3) * 8 + bg) * 2) * 4096;
        const int unitc = (kh * 16 + kg) * 32 + mh * 16 + lrow;
        u32x4 vh[4], vl[4];
#pragma unroll
        for (int kt = 0; kt < 4; ++kt)
          vh[kt] = ldx4_cc(base + (unitc + kt * 4 * 32) * 4);
#pragma unroll
        for (int kt = 0; kt < 4; ++kt)
          vl[kt] = ldx4_cc(base + 4096 + (unitc + kt * 4 * 32) * 4);
        vm_wait4();                             // hi-plane loads complete
        __builtin_amdgcn_sched_barrier(0);
#pragma unroll
        for (int kt = 0; kt < 4; ++kt) {
          short8 ahi = u2s8(vh[kt]);
#pragma unroll
          for (int n = 0; n < 4; ++n) {
            acc[n] = mfma16(ahi, Bhi[1][kt][n], acc[n]);
            acc[n] = mfma16(ahi, Blo[1][kt][n], acc[n]);
          }
        }
        vm_drain();                             // lo-plane loads complete
        __builtin_amdgcn_sched_barrier(0);
#pragma unroll
        for (int kt = 0; kt < 4; ++kt) {
          short8 alo = u2s8(vl[kt]);
#pragma unroll
          for (int n = 0; n < 4; ++n)
            acc[n] = mfma16(alo, Bhi[1][kt][n], acc[n]);
        }
      }

      if (kh == 1) {
#pragma unroll
        for (int n = 0; n < 4; ++n) pg[mh][n][lane] = acc[n];
      }
      __syncthreads();
      if (kh == 0) {
#pragma unroll
        for (int n = 0; n < 4; ++n) acc[n] += pg[mh][n][lane];
#pragma unroll
        for (int r = 0; r < 4; ++r) {
          float gi = acc[0][r] + bias[0];
          float gf = acc[1][r] + bias[1];
          float gg = acc[2][r] + bias[2];
          float go = acc[3][r] + bias[3];
          float cc = sigf(gf) * cst[r] + sigf(gi) * tanh_fast(gg);
          cst[r] = cc;
          float hv = sigf(go) * tanh_fast(cc);
          const int b = mh * 16 + kg * 4 + r;
          unsigned short hh = f2bf(hv);
          unsigned short hl = f2bf(hv - bf2f(hh));
          hbuf[b][lrow] = (uint32_t)hh | ((uint32_t)hl << 16);
        }
      }
      __syncthreads();                          // hbuf ready
      {
        uint32_t* base = h0d + (size_t)(((t & 3) * 8 + bg) * 2) * 4096;
        uint32_t* dstp = (pp == 0) ? base : base + 4096;
        uint32_t w0 = hbuf[srow][scc],     w1 = hbuf[srow][scc + 1];
        uint32_t w2 = hbuf[srow][scc + 2], w3 = hbuf[srow][scc + 3];
        u32x2 val;
        if (pp == 0) {
          val[0] = (w0 & 0xffffu) | (w1 << 16);
          val[1] = (w2 & 0xffffu) | (w3 << 16);
        } else {
          val[0] = (w0 >> 16) | (w1 & 0xffff0000u);
          val[1] = (w2 >> 16) | (w3 & 0xffff0000u);
        }
        stx2_cc(dstp + sug * 4 + sj0, val);
      }
      vm_drain();                               // this wave's h stores ack'd
      if (lane == 0)
        __hip_atomic_store(my_slot, (uint32_t)(t + 1), __ATOMIC_RELAXED,
                           __HIP_MEMORY_SCOPE_AGENT);
    }
  } else {
    // ------------------------------ layer 1 --------------------------------
    for (int s = 0; s < TT; ++s) {
      // ONE combined wait: h0[s] ready (flags0 >= s+1) AND peers done s-1
      // (flags1 >= s; also write-after-read for the h1 ring).
      if (wave == 0)
        poll_combined(fbg, (uint32_t)(s + 1), (uint32_t)s, lane);
      __syncthreads();

      const uint32_t* b1 =
          h1d + (size_t)((((s - 1) & 1) * 8 + bg) * 2) * 4096;
      const uint32_t* b0 = h0d + (size_t)(((s & 3) * 8 + bg) * 2) * 4096;
      const int unitc = (kh * 16 + kg) * 32 + mh * 16 + lrow;
      u32x4 y1h[4], y1l[4], y0h[4], y0l[4];
#pragma unroll
      for (int kt = 0; kt < 4; ++kt)
        y1h[kt] = ldx4_cc(b1 + (unitc + kt * 4 * 32) * 4);
#pragma unroll
      for (int kt = 0; kt < 4; ++kt)
        y1l[kt] = ldx4_cc(b1 + 4096 + (unitc + kt * 4 * 32) * 4);
#pragma unroll
      for (int kt = 0; kt < 4; ++kt)
        y0h[kt] = ldx4_cc(b0 + (unitc + kt * 4 * 32) * 4);
#pragma unroll
      for (int kt = 0; kt < 4; ++kt)
        y0l[kt] = ldx4_cc(b0 + 4096 + (unitc + kt * 4 * 32) * 4);

      f32x4 acc[4];
#pragma unroll
      for (int n = 0; n < 4; ++n) acc[n] = (f32x4)(0.0f);

      vm_wait8();                               // h1 loads complete
      __builtin_amdgcn_sched_barrier(0);
#pragma unroll
      for (int kt = 0; kt < 4; ++kt) {          // input 1: h1[s-1]
        short8 ahi = u2s8(y1h[kt]);
        short8 alo = u2s8(y1l[kt]);
#pragma unroll
        for (int n = 0; n < 4; ++n) {
          acc[n] = mfma16(ahi, Bhi[1][kt][n], acc[n]);
          acc[n] = mfma16(alo, Bhi[1][kt][n], acc[n]);
          acc[n] = mfma16(ahi, Blo[1][kt][n], acc[n]);
        }
      }
      vm_drain();                               // h0 loads complete
      __builtin_amdgcn_sched_barrier(0);
#pragma unroll
      for (int kt = 0; kt < 4; ++kt) {          // input 0: h0[s]
        short8 ahi = u2s8(y0h[kt]);
        short8 alo = u2s8(y0l[kt]);
#pragma unroll
        for (int n = 0; n < 4; ++n) {
          acc[n] = mfma16(ahi, Bhi[0][kt][n], acc[n]);
          acc[n] = mfma16(alo, Bhi[0][kt][n], acc[n]);
          acc[n] = mfma16(ahi, Blo[0][kt][n], acc[n]);
        }
      }

      if (kh == 1) {
#pragma unroll
        for (int n = 0; n < 4; ++n) pg[mh][n][lane] = acc[n];
      }
      __syncthreads();
      if (kh == 0) {
#pragma unroll
        for (int n = 0; n < 4; ++n) acc[n] += pg[mh][n][lane];
        float hva[4];
#pragma unroll
        for (int r = 0; r < 4; ++r) {
          float gi = acc[0][r] + bias[0];
          float gf = acc[1][r] + bias[1];
          float gg = acc[2][r] + bias[2];
          float go = acc[3][r] + bias[3];
          float cc = sigf(gf) * cst[r] + sigf(gi) * tanh_fast(gg);
          cst[r] = cc;
          float hv = sigf(go) * tanh_fast(cc);
          hva[r] = hv;
          const int b = mh * 16 + kg * 4 + r;
          unsigned short hh = f2bf(hv);
          unsigned short hl = f2bf(hv - bf2f(hh));
          hbuf[b][lrow] = (uint32_t)hh | ((uint32_t)hl << 16);
        }
        if (s == TT - 1) {
          // out[b] = sum_f h1[b,f] * Whead[f] + b_head
#pragma unroll
          for (int r = 0; r < 4; ++r) {
            float v = hva[r] * wh;
            v += __shfl_xor(v, 1);
            v += __shfl_xor(v, 2);
            v += __shfl_xor(v, 4);
            v += __shfl_xor(v, 8);
            if (lrow == 0) {
              float add = v + (fs == 0 ? bh : 0.0f);
              atomicAdd(out + bg * 32 + mh * 16 + kg * 4 + r, add);
            }
          }
        }
      }
      __syncthreads();                          // hbuf ready
      {
        uint32_t* base = h1d + (size_t)(((s & 1) * 8 + bg) * 2) * 4096;
        uint32_t* dstp = (pp == 0) ? base : base + 4096;
        uint32_t w0 = hbuf[srow][scc],     w1 = hbuf[srow][scc + 1];
        uint32_t w2 = hbuf[srow][scc + 2], w3 = hbuf[srow][scc + 3];
        u32x2 val;
        if (pp == 0) {
          val[0] = (w0 & 0xffffu) | (w1 << 16);
          val[1] = (w2 & 0xffffu) | (w3 << 16);
        } else {
          val[0] = (w0 >> 16) | (w1 & 0xffff0000u);
          val[1] = (w2 >> 16) | (w3 & 0xffff0000u);
        }
        stx2_cc(dstp + sug * 4 + sj0, val);
      }
      vm_drain();                               // this wave's h stores ack'd
      if (lane == 0)
        __hip_atomic_store(my_slot, (uint32_t)(s + 1), __ATOMIC_RELAXED,
                           __HIP_MEMORY_SCOPE_AGENT);
    }
  }
}

extern "C" void kernel_launch(void* const* d_in, const int* in_sizes, int n_in,
                              void* d_out, int out_size, void* d_ws, size_t ws_size,
                              hipStream_t stream) {
  (void)in_sizes; (void)n_in; (void)ws_size;
  const float* x     = (const float*)d_in[0];
  const float* Wih0  = (const float*)d_in[1];
  const float* Whh0  = (const float*)d_in[2];
  const float* bih0  = (const float*)d_in[3];
  const float* bhh0  = (const float*)d_in[4];
  const float* Wih1  = (const float*)d_in[5];
  const float* Whh1  = (const float*)d_in[6];
  const float* bih1  = (const float*)d_in[7];
  const float* bhh1  = (const float*)d_in[8];
  const float* Whead = (const float*)d_in[9];
  const float* bhead = (const float*)d_in[10];

  hipMemsetAsync(d_ws, 0, WS_BYTES, stream);                 // h bufs + flags
  hipMemsetAsync(d_out, 0, (size_t)out_size * sizeof(float), stream);
  lstm2_kernel<<<dim3(256), dim3(256), 0, stream>>>(
      x, Wih0, Whh0, bih0, bhh0, Wih1, Whh1, bih1, bhh1, Whead, bhead,
      (float*)d_out, (uint8_t*)d_ws);
}